// Round 1
// baseline (434.853 us; speedup 1.0000x reference)
//
#include <hip/hip_runtime.h>
#include <math.h>

// Problem constants (match reference)
constexpr int BB = 32;
constexpr int SS = 8192;
constexpr int DD = 256;          // D_ENC == D_DEC == D_CTX
constexpr int SCHUNK = 256;      // rows per block in main pass
constexpr int NCHUNK = SS / SCHUNK;  // 32 chunks per batch
constexpr float NEG_SLOPE = 0.2f;
constexpr float MASK_VAL = -10000.0f;

// ---------------------------------------------------------------------------
// Kernel 1: v[b,e] = sum_d ht[b,d] * Wa_w[d,e];  c0[b] = ht[b,:] . Wa_b
// ---------------------------------------------------------------------------
__global__ __launch_bounds__(256) void attn_prep(
    const float* __restrict__ ht, const float* __restrict__ Wa_w,
    const float* __restrict__ Wa_b, float* __restrict__ v,
    float* __restrict__ c0)
{
    const int b = blockIdx.x;
    const int t = threadIdx.x;
    __shared__ float sht[DD];
    __shared__ float red[256];
    sht[t] = ht[b * DD + t];
    __syncthreads();
    float acc = 0.f;
    #pragma unroll 8
    for (int d = 0; d < DD; ++d)
        acc = fmaf(sht[d], Wa_w[d * DD + t], acc);   // coalesced in t
    v[b * DD + t] = acc;
    // c0 reduction
    red[t] = sht[t] * Wa_b[t];
    __syncthreads();
    for (int s2 = 128; s2 > 0; s2 >>= 1) {
        if (t < s2) red[t] += red[t + s2];
        __syncthreads();
    }
    if (t == 0) c0[b] = red[0];
}

// ---------------------------------------------------------------------------
// Kernel 2: streaming pass over hs. One wave per row; online softmax with
// rescaled accumulation of u = sum exp(e - m) * hs_row. Writes raw post-mask
// energies and per-(b,chunk) partials [m, l, u[256]] (stride 258 floats).
// ---------------------------------------------------------------------------
__global__ __launch_bounds__(256) void attn_main(
    const float* __restrict__ hs, const float* __restrict__ v,
    const float* __restrict__ c0, const int* __restrict__ slen,
    float* __restrict__ energy, float* __restrict__ part)
{
    const int b     = blockIdx.y;
    const int chunk = blockIdx.x;
    const int wave  = threadIdx.x >> 6;
    const int lane  = threadIdx.x & 63;

    const int   len = slen[b];
    const float c0b = c0[b];
    const float4 vv = *(const float4*)(v + b * DD + lane * 4);

    const int s_base = chunk * SCHUNK + wave * 64;
    const float* hrow = hs + ((long)b * SS + s_base) * DD + lane * 4;

    float  m = -INFINITY, l = 0.f;
    float4 u = {0.f, 0.f, 0.f, 0.f};
    float  my_e = 0.f;   // energy of row (s_base + lane), captured when i == lane

    for (int i = 0; i < 64; ++i) {
        const float4 h = *(const float4*)(hrow + (long)i * DD);
        float d = h.x * vv.x + h.y * vv.y + h.z * vv.z + h.w * vv.w;
        d += __shfl_xor(d, 32); d += __shfl_xor(d, 16); d += __shfl_xor(d, 8);
        d += __shfl_xor(d, 4);  d += __shfl_xor(d, 2);  d += __shfl_xor(d, 1);
        float e = d + c0b;
        e = e > 0.f ? e : NEG_SLOPE * e;                 // leaky relu
        if (s_base + i >= len) e = MASK_VAL;             // length mask
        if (lane == i) my_e = e;
        const float mn = fmaxf(m, e);
        const float sc = __expf(m - mn);                 // first iter: exp(-inf)=0
        const float w  = __expf(e - mn);
        l = l * sc + w;
        u.x = fmaf(w, h.x, u.x * sc);
        u.y = fmaf(w, h.y, u.y * sc);
        u.z = fmaf(w, h.z, u.z * sc);
        u.w = fmaf(w, h.w, u.w * sc);
        m = mn;
    }
    // coalesced energy store: lane holds row (s_base+lane)'s energy
    energy[(long)b * SS + s_base + lane] = my_e;

    // combine 4 waves -> one chunk partial
    __shared__ float wm[4], wl[4];
    __shared__ float wu[4][DD];
    if (lane == 0) { wm[wave] = m; wl[wave] = l; }
    *(float4*)&wu[wave][lane * 4] = u;
    __syncthreads();

    const float M  = fmaxf(fmaxf(wm[0], wm[1]), fmaxf(wm[2], wm[3]));
    const float s0 = __expf(wm[0] - M), s1 = __expf(wm[1] - M);
    const float s2 = __expf(wm[2] - M), s3 = __expf(wm[3] - M);
    const int t = threadIdx.x;
    const float uu = wu[0][t] * s0 + wu[1][t] * s1 + wu[2][t] * s2 + wu[3][t] * s3;

    float* p = part + ((long)b * NCHUNK + chunk) * 258;
    if (t == 0) {
        p[0] = M;
        p[1] = wl[0] * s0 + wl[1] * s1 + wl[2] * s2 + wl[3] * s3;
    }
    p[2 + t] = uu;
}

// ---------------------------------------------------------------------------
// Kernel 3: per-batch merge of chunk partials -> global (M, L); context
// context[b,c] = Wc_w[c,:] . (u/L) + Wc_b[c]
// ---------------------------------------------------------------------------
__global__ __launch_bounds__(256) void attn_reduce(
    const float* __restrict__ part, const float* __restrict__ Wc_w,
    const float* __restrict__ Wc_b, float* __restrict__ ml,
    float* __restrict__ ctx)
{
    const int b = blockIdx.x;
    const int t = threadIdx.x;
    const int wave = t >> 6, lane = t & 63;
    __shared__ float su[DD];
    __shared__ float sm[NCHUNK], sl[NCHUNK];

    if (t < NCHUNK) {
        const float* p = part + ((long)b * NCHUNK + t) * 258;
        sm[t] = p[0];
        sl[t] = p[1];
    }
    __syncthreads();

    float M = -INFINITY;
    #pragma unroll
    for (int i = 0; i < NCHUNK; ++i) M = fmaxf(M, sm[i]);
    float L = 0.f, u = 0.f;
    for (int i = 0; i < NCHUNK; ++i) {
        const float sc = __expf(sm[i] - M);
        L += sl[i] * sc;
        u = fmaf(part[((long)b * NCHUNK + i) * 258 + 2 + t], sc, u);
    }
    su[t] = u / L;
    if (t == 0) { ml[2 * b] = M; ml[2 * b + 1] = L; }
    __syncthreads();

    const float4 s4 = *(const float4*)&su[lane * 4];
    for (int c = wave; c < DD; c += 4) {
        const float4 w4 = *(const float4*)(Wc_w + c * DD + lane * 4);
        float d = w4.x * s4.x + w4.y * s4.y + w4.z * s4.z + w4.w * s4.w;
        d += __shfl_xor(d, 32); d += __shfl_xor(d, 16); d += __shfl_xor(d, 8);
        d += __shfl_xor(d, 4);  d += __shfl_xor(d, 2);  d += __shfl_xor(d, 1);
        if (lane == 0) ctx[b * DD + c] = d + Wc_b[c];
    }
}

// ---------------------------------------------------------------------------
// Kernel 4: alpha[b,s] = exp(energy - M) / L    (float4 elementwise)
// ---------------------------------------------------------------------------
__global__ __launch_bounds__(256) void attn_alpha(
    const float* __restrict__ energy, const float* __restrict__ ml,
    float* __restrict__ alpha)
{
    const int idx = blockIdx.x * 256 + threadIdx.x;  // float4 units, B*S/4 total
    const int b = idx >> 11;                         // 2048 float4 per batch
    const float M    = ml[2 * b];
    const float invL = 1.0f / ml[2 * b + 1];
    const float4 e4 = ((const float4*)energy)[idx];
    float4 a;
    a.x = __expf(e4.x - M) * invL;
    a.y = __expf(e4.y - M) * invL;
    a.z = __expf(e4.z - M) * invL;
    a.w = __expf(e4.w - M) * invL;
    ((float4*)alpha)[idx] = a;
}

// ---------------------------------------------------------------------------
extern "C" void kernel_launch(void* const* d_in, const int* in_sizes, int n_in,
                              void* d_out, int out_size, void* d_ws, size_t ws_size,
                              hipStream_t stream)
{
    const float* hs    = (const float*)d_in[0];
    const float* ht    = (const float*)d_in[1];
    const int*   slen  = (const int*)d_in[2];
    const float* Wa_w  = (const float*)d_in[3];
    const float* Wa_b  = (const float*)d_in[4];
    const float* Wc_w  = (const float*)d_in[5];
    const float* Wc_b  = (const float*)d_in[6];

    float* alpha = (float*)d_out;                 // [B, S]
    float* ctx   = (float*)d_out + (long)BB * SS; // [B, D_CTX]

    // workspace layout (floats)
    float* ws     = (float*)d_ws;
    float* v      = ws;                       //  8192
    float* c0     = ws + 8192;                //    32
    float* ml     = ws + 8224;                //    64
    float* energy = ws + 8288;                // 262144
    float* part   = ws + 270432;              // 32*32*258 = 264192

    attn_prep<<<BB, 256, 0, stream>>>(ht, Wa_w, Wa_b, v, c0);
    attn_main<<<dim3(NCHUNK, BB), 256, 0, stream>>>(hs, v, c0, slen, energy, part);
    attn_reduce<<<BB, 256, 0, stream>>>(part, Wc_w, Wc_b, ml, ctx);
    attn_alpha<<<(BB * SS / 4) / 256, 256, 0, stream>>>(energy, ml, alpha);
}

// Round 3
// 414.339 us; speedup vs baseline: 1.0495x; 1.0495x over previous
//
#include <hip/hip_runtime.h>
#include <math.h>

// Problem constants (match reference)
constexpr int BB = 32;
constexpr int SS = 8192;
constexpr int DD = 256;          // D_ENC == D_DEC == D_CTX
constexpr int SCHUNK = 128;      // rows per block in main pass (32 rows/wave)
constexpr int NCHUNK = SS / SCHUNK;  // 64 chunks per batch
constexpr float NEG_SLOPE = 0.2f;
constexpr float MASK_VAL = -10000.0f;

// clang ext vector type — required by __builtin_nontemporal_load/store
typedef float f4 __attribute__((ext_vector_type(4)));

__device__ __forceinline__ float dot4(const f4 a, const f4 b) {
    return a.x * b.x + a.y * b.y + a.z * b.z + a.w * b.w;
}

// ---------------------------------------------------------------------------
// Kernel 1: v[b,e] = sum_d ht[b,d] * Wa_w[d,e];  c0[b] = ht[b,:] . Wa_b
// ---------------------------------------------------------------------------
__global__ __launch_bounds__(256) void attn_prep(
    const float* __restrict__ ht, const float* __restrict__ Wa_w,
    const float* __restrict__ Wa_b, float* __restrict__ v,
    float* __restrict__ c0)
{
    const int b = blockIdx.x;
    const int t = threadIdx.x;
    __shared__ float sht[DD];
    __shared__ float red[256];
    sht[t] = ht[b * DD + t];
    __syncthreads();
    float acc = 0.f;
    #pragma unroll 8
    for (int d = 0; d < DD; ++d)
        acc = fmaf(sht[d], Wa_w[d * DD + t], acc);   // coalesced in t
    v[b * DD + t] = acc;
    red[t] = sht[t] * Wa_b[t];
    __syncthreads();
    for (int s2 = 128; s2 > 0; s2 >>= 1) {
        if (t < s2) red[t] += red[t + s2];
        __syncthreads();
    }
    if (t == 0) c0[b] = red[0];
}

// ---------------------------------------------------------------------------
// Kernel 2: streaming pass over hs. Each wave handles 32 rows, processed in
// PAIRS: paired butterfly reduction (8 shuffles / 2 rows), one online-softmax
// rescale per pair, software-pipelined nontemporal loads.
// ---------------------------------------------------------------------------
__global__ __launch_bounds__(256) void attn_main(
    const float* __restrict__ hs, const float* __restrict__ v,
    const float* __restrict__ c0, const int* __restrict__ slen,
    float* __restrict__ energy, float* __restrict__ part)
{
    const int b     = blockIdx.y;
    const int chunk = blockIdx.x;
    const int wave  = threadIdx.x >> 6;
    const int lane  = threadIdx.x & 63;

    const int   len = slen[b];
    const float c0b = c0[b];
    const f4 vv = *(const f4*)(v + b * DD + lane * 4);

    const int s_base = chunk * SCHUNK + wave * 32;         // 32 rows per wave
    const f4* hrow = (const f4*)(hs + ((long)b * SS + s_base) * DD) + lane;
    constexpr int RSTRIDE = DD / 4;                        // f4 per row

    float m = -INFINITY, l = 0.f;
    f4 u = {0.f, 0.f, 0.f, 0.f};
    float my_e = 0.f;   // lane i (<32) captures energy of row s_base+i

    f4 h0 = __builtin_nontemporal_load(hrow);
    f4 h1 = __builtin_nontemporal_load(hrow + RSTRIDE);

    #pragma unroll 4
    for (int p = 0; p < 16; ++p) {
        f4 n0, n1;
        if (p < 15) {
            n0 = __builtin_nontemporal_load(hrow + (2 * p + 2) * RSTRIDE);
            n1 = __builtin_nontemporal_load(hrow + (2 * p + 3) * RSTRIDE);
        }
        // paired cross-lane reduction of two dot products
        float d0 = dot4(h0, vv);
        float d1 = dot4(h1, vv);
        const float t0 = __shfl_xor(d0, 32);
        const float t1 = __shfl_xor(d1, 32);
        float x = (lane < 32) ? (d0 + t0) : (d1 + t1);
        x += __shfl_xor(x, 16);
        x += __shfl_xor(x, 8);
        x += __shfl_xor(x, 4);
        x += __shfl_xor(x, 2);
        x += __shfl_xor(x, 1);
        const float y = __shfl_xor(x, 32);
        float e0 = ((lane < 32) ? x : y) + c0b;
        float e1 = ((lane < 32) ? y : x) + c0b;

        const int r0 = s_base + 2 * p;
        e0 = e0 > 0.f ? e0 : NEG_SLOPE * e0;
        e1 = e1 > 0.f ? e1 : NEG_SLOPE * e1;
        if (r0 >= len)     e0 = MASK_VAL;
        if (r0 + 1 >= len) e1 = MASK_VAL;
        if (lane == 2 * p)     my_e = e0;
        if (lane == 2 * p + 1) my_e = e1;

        // online softmax update, one rescale per pair
        const float mn = fmaxf(m, fmaxf(e0, e1));
        const float sc = __expf(m - mn);     // first pair: exp(-inf)=0
        const float w0 = __expf(e0 - mn);
        const float w1 = __expf(e1 - mn);
        l = l * sc + w0 + w1;
        u.x = fmaf(w1, h1.x, fmaf(w0, h0.x, u.x * sc));
        u.y = fmaf(w1, h1.y, fmaf(w0, h0.y, u.y * sc));
        u.z = fmaf(w1, h1.z, fmaf(w0, h0.z, u.z * sc));
        u.w = fmaf(w1, h1.w, fmaf(w0, h0.w, u.w * sc));
        m = mn;
        h0 = n0; h1 = n1;
    }
    // coalesced energy store: lanes 0..31 hold rows s_base..s_base+31
    if (lane < 32)
        __builtin_nontemporal_store(my_e, &energy[(long)b * SS + s_base + lane]);

    // combine 4 waves -> one chunk partial
    __shared__ float wm[4], wl[4];
    __shared__ float wu[4][DD];
    if (lane == 0) { wm[wave] = m; wl[wave] = l; }
    *(f4*)&wu[wave][lane * 4] = u;
    __syncthreads();

    const float M  = fmaxf(fmaxf(wm[0], wm[1]), fmaxf(wm[2], wm[3]));
    const float s0 = __expf(wm[0] - M), s1 = __expf(wm[1] - M);
    const float s2 = __expf(wm[2] - M), s3 = __expf(wm[3] - M);
    const int t = threadIdx.x;
    const float uu = wu[0][t] * s0 + wu[1][t] * s1 + wu[2][t] * s2 + wu[3][t] * s3;

    float* p = part + ((long)b * NCHUNK + chunk) * 258;
    if (t == 0) {
        p[0] = M;
        p[1] = wl[0] * s0 + wl[1] * s1 + wl[2] * s2 + wl[3] * s3;
    }
    p[2 + t] = uu;
}

// ---------------------------------------------------------------------------
// Kernel 3: per-batch merge of chunk partials -> global (M, L); context
// ---------------------------------------------------------------------------
__global__ __launch_bounds__(256) void attn_reduce(
    const float* __restrict__ part, const float* __restrict__ Wc_w,
    const float* __restrict__ Wc_b, float* __restrict__ ml,
    float* __restrict__ ctx)
{
    const int b = blockIdx.x;
    const int t = threadIdx.x;
    const int wave = t >> 6, lane = t & 63;
    __shared__ float su[DD];
    __shared__ float sm[NCHUNK], sl[NCHUNK];

    if (t < NCHUNK) {
        const float* p = part + ((long)b * NCHUNK + t) * 258;
        sm[t] = p[0];
        sl[t] = p[1];
    }
    __syncthreads();

    float M = -INFINITY;
    #pragma unroll
    for (int i = 0; i < NCHUNK; ++i) M = fmaxf(M, sm[i]);
    float L = 0.f, u = 0.f;
    for (int i = 0; i < NCHUNK; ++i) {
        const float sc = __expf(sm[i] - M);
        L += sl[i] * sc;
        u = fmaf(part[((long)b * NCHUNK + i) * 258 + 2 + t], sc, u);
    }
    su[t] = u / L;
    if (t == 0) { ml[2 * b] = M; ml[2 * b + 1] = L; }
    __syncthreads();

    const f4 s4 = *(const f4*)&su[lane * 4];
    for (int c = wave; c < DD; c += 4) {
        const f4 w4 = *(const f4*)(Wc_w + c * DD + lane * 4);
        float d = dot4(w4, s4);
        d += __shfl_xor(d, 32); d += __shfl_xor(d, 16); d += __shfl_xor(d, 8);
        d += __shfl_xor(d, 4);  d += __shfl_xor(d, 2);  d += __shfl_xor(d, 1);
        if (lane == 0) ctx[b * DD + c] = d + Wc_b[c];
    }
}

// ---------------------------------------------------------------------------
// Kernel 4: alpha[b,s] = exp(energy - M) / L    (f4 elementwise)
// ---------------------------------------------------------------------------
__global__ __launch_bounds__(256) void attn_alpha(
    const float* __restrict__ energy, const float* __restrict__ ml,
    float* __restrict__ alpha)
{
    const int idx = blockIdx.x * 256 + threadIdx.x;  // f4 units
    const int b = idx >> 11;                         // 2048 f4 per batch
    const float M    = ml[2 * b];
    const float invL = 1.0f / ml[2 * b + 1];
    const f4 e4 = __builtin_nontemporal_load(((const f4*)energy) + idx);
    f4 a;
    a.x = __expf(e4.x - M) * invL;
    a.y = __expf(e4.y - M) * invL;
    a.z = __expf(e4.z - M) * invL;
    a.w = __expf(e4.w - M) * invL;
    __builtin_nontemporal_store(a, ((f4*)alpha) + idx);
}

// ---------------------------------------------------------------------------
extern "C" void kernel_launch(void* const* d_in, const int* in_sizes, int n_in,
                              void* d_out, int out_size, void* d_ws, size_t ws_size,
                              hipStream_t stream)
{
    const float* hs    = (const float*)d_in[0];
    const float* ht    = (const float*)d_in[1];
    const int*   slen  = (const int*)d_in[2];
    const float* Wa_w  = (const float*)d_in[3];
    const float* Wa_b  = (const float*)d_in[4];
    const float* Wc_w  = (const float*)d_in[5];
    const float* Wc_b  = (const float*)d_in[6];

    float* alpha = (float*)d_out;                 // [B, S]
    float* ctx   = (float*)d_out + (long)BB * SS; // [B, D_CTX]

    // workspace layout (floats)
    float* ws     = (float*)d_ws;
    float* v      = ws;                        //  8192
    float* c0     = ws + 8192;                 //    32
    float* ml     = ws + 8224;                 //    64
    float* energy = ws + 8288;                 // 262144
    float* part   = ws + 270432;               // 32*64*258 = 528384

    attn_prep<<<BB, 256, 0, stream>>>(ht, Wa_w, Wa_b, v, c0);
    attn_main<<<dim3(NCHUNK, BB), 256, 0, stream>>>(hs, v, c0, slen, energy, part);
    attn_reduce<<<BB, 256, 0, stream>>>(part, Wc_w, Wc_b, ml, ctx);
    attn_alpha<<<(BB * SS / 4) / 256, 256, 0, stream>>>(energy, ml, alpha);
}

// Round 4
// 387.075 us; speedup vs baseline: 1.1234x; 1.0704x over previous
//
#include <hip/hip_runtime.h>
#include <math.h>

// Problem constants (match reference)
constexpr int BB = 32;
constexpr int SS = 8192;
constexpr int DD = 256;          // D_ENC == D_DEC == D_CTX
constexpr int SCHUNK = 128;      // rows per block in main pass (32 rows/wave)
constexpr int NCHUNK = SS / SCHUNK;  // 64 chunks per batch
constexpr float NEG_SLOPE = 0.2f;
constexpr float MASK_VAL = -10000.0f;

// clang ext vector type — required by __builtin_nontemporal_load/store
typedef float f4 __attribute__((ext_vector_type(4)));

__device__ __forceinline__ float dot4(const f4 a, const f4 b) {
    return a.x * b.x + a.y * b.y + a.z * b.z + a.w * b.w;
}

// ---------------------------------------------------------------------------
// Kernel 1: v[b,e] = sum_d ht[b,d] * Wa_w[d,e];  c0[b] = ht[b,:] . Wa_b
// grid (4, BB): each block computes 64 columns, d-loop split 4-ways for MLP.
// ---------------------------------------------------------------------------
__global__ __launch_bounds__(256) void attn_prep(
    const float* __restrict__ ht, const float* __restrict__ Wa_w,
    const float* __restrict__ Wa_b, float* __restrict__ v,
    float* __restrict__ c0)
{
    const int b   = blockIdx.y;
    const int cg  = blockIdx.x;          // column group of 64
    const int t   = threadIdx.x;
    const int col = cg * 64 + (t & 63);
    const int dp  = t >> 6;              // d-partition 0..3
    __shared__ float sht[DD];
    __shared__ float red[4][64];
    sht[t] = ht[b * DD + t];
    __syncthreads();
    float acc = 0.f;
    #pragma unroll 16
    for (int i = 0; i < 64; ++i) {
        const int d = dp * 64 + i;
        acc = fmaf(sht[d], Wa_w[d * DD + col], acc);  // 256B coalesced per dp
    }
    red[dp][t & 63] = acc;
    __syncthreads();
    if (t < 64)
        v[b * DD + col] = red[0][t] + red[1][t] + red[2][t] + red[3][t];

    if (cg == 0) {                       // c0[b] = ht . Wa_b
        __syncthreads();
        float* fr = &red[0][0];
        fr[t] = sht[t] * Wa_b[t];
        __syncthreads();
        for (int s2 = 128; s2 > 0; s2 >>= 1) {
            if (t < s2) fr[t] += fr[t + s2];
            __syncthreads();
        }
        if (t == 0) c0[b] = fr[0];
    }
}

// ---------------------------------------------------------------------------
// Kernel 2: streaming pass over hs. Fully-masked blocks (len>0) skip their hs
// reads entirely: reference's exp(MASK_VAL - M) underflows to exact 0 in fp32
// whenever any valid row exists, so their contribution is identically zero.
// len==0 takes the normal path (uniform weights), which is exact.
// ---------------------------------------------------------------------------
__global__ __launch_bounds__(256) void attn_main(
    const float* __restrict__ hs, const float* __restrict__ v,
    const float* __restrict__ c0, const int* __restrict__ slen,
    float* __restrict__ energy, float* __restrict__ part)
{
    const int b     = blockIdx.y;
    const int chunk = blockIdx.x;
    const int wave  = threadIdx.x >> 6;
    const int lane  = threadIdx.x & 63;
    const int t     = threadIdx.x;

    const int len = slen[b];

    if (len > 0 && chunk * SCHUNK >= len) {
        // fully-masked block: no hs read needed
        if (t < SCHUNK)
            __builtin_nontemporal_store(
                MASK_VAL, &energy[(long)b * SS + chunk * SCHUNK + t]);
        float* p = part + ((long)b * NCHUNK + chunk) * 258;
        if (t == 0) { p[0] = -INFINITY; p[1] = 0.f; }
        p[2 + t] = 0.f;
        return;
    }

    const float c0b = c0[b];
    const f4 vv = *(const f4*)(v + b * DD + lane * 4);

    const int s_base = chunk * SCHUNK + wave * 32;         // 32 rows per wave
    const f4* hrow = (const f4*)(hs + ((long)b * SS + s_base) * DD) + lane;
    constexpr int RSTRIDE = DD / 4;                        // f4 per row

    float m = -INFINITY, l = 0.f;
    f4 u = {0.f, 0.f, 0.f, 0.f};
    float my_e = 0.f;   // lane i (<32) captures energy of row s_base+i

    f4 h0 = __builtin_nontemporal_load(hrow);
    f4 h1 = __builtin_nontemporal_load(hrow + RSTRIDE);

    #pragma unroll 4
    for (int p = 0; p < 16; ++p) {
        f4 n0, n1;
        if (p < 15) {
            n0 = __builtin_nontemporal_load(hrow + (2 * p + 2) * RSTRIDE);
            n1 = __builtin_nontemporal_load(hrow + (2 * p + 3) * RSTRIDE);
        }
        // paired cross-lane reduction of two dot products
        float d0 = dot4(h0, vv);
        float d1 = dot4(h1, vv);
        const float t0 = __shfl_xor(d0, 32);
        const float t1 = __shfl_xor(d1, 32);
        float x = (lane < 32) ? (d0 + t0) : (d1 + t1);
        x += __shfl_xor(x, 16);
        x += __shfl_xor(x, 8);
        x += __shfl_xor(x, 4);
        x += __shfl_xor(x, 2);
        x += __shfl_xor(x, 1);
        const float y = __shfl_xor(x, 32);
        float e0 = ((lane < 32) ? x : y) + c0b;
        float e1 = ((lane < 32) ? y : x) + c0b;

        const int r0 = s_base + 2 * p;
        e0 = e0 > 0.f ? e0 : NEG_SLOPE * e0;
        e1 = e1 > 0.f ? e1 : NEG_SLOPE * e1;
        if (r0 >= len)     e0 = MASK_VAL;
        if (r0 + 1 >= len) e1 = MASK_VAL;
        if (lane == 2 * p)     my_e = e0;
        if (lane == 2 * p + 1) my_e = e1;

        // online softmax update, one rescale per pair
        const float mn = fmaxf(m, fmaxf(e0, e1));
        const float sc = __expf(m - mn);     // first pair: exp(-inf)=0
        const float w0 = __expf(e0 - mn);
        const float w1 = __expf(e1 - mn);
        l = l * sc + w0 + w1;
        u.x = fmaf(w1, h1.x, fmaf(w0, h0.x, u.x * sc));
        u.y = fmaf(w1, h1.y, fmaf(w0, h0.y, u.y * sc));
        u.z = fmaf(w1, h1.z, fmaf(w0, h0.z, u.z * sc));
        u.w = fmaf(w1, h1.w, fmaf(w0, h0.w, u.w * sc));
        m = mn;
        h0 = n0; h1 = n1;
    }
    // coalesced energy store: lanes 0..31 hold rows s_base..s_base+31
    if (lane < 32)
        __builtin_nontemporal_store(my_e, &energy[(long)b * SS + s_base + lane]);

    // combine 4 waves -> one chunk partial
    __shared__ float wm[4], wl[4];
    __shared__ float wu[4][DD];
    if (lane == 0) { wm[wave] = m; wl[wave] = l; }
    *(f4*)&wu[wave][lane * 4] = u;
    __syncthreads();

    const float M  = fmaxf(fmaxf(wm[0], wm[1]), fmaxf(wm[2], wm[3]));
    const float s0 = __expf(wm[0] - M), s1 = __expf(wm[1] - M);
    const float s2 = __expf(wm[2] - M), s3 = __expf(wm[3] - M);
    const float uu = wu[0][t] * s0 + wu[1][t] * s1 + wu[2][t] * s2 + wu[3][t] * s3;

    float* p = part + ((long)b * NCHUNK + chunk) * 258;
    if (t == 0) {
        p[0] = M;
        p[1] = wl[0] * s0 + wl[1] * s1 + wl[2] * s2 + wl[3] * s3;
    }
    p[2 + t] = uu;
}

// ---------------------------------------------------------------------------
// Kernel 3: per-batch merge of chunk partials -> global (M, L); context
// ---------------------------------------------------------------------------
__global__ __launch_bounds__(256) void attn_reduce(
    const float* __restrict__ part, const float* __restrict__ Wc_w,
    const float* __restrict__ Wc_b, float* __restrict__ ml,
    float* __restrict__ ctx)
{
    const int b = blockIdx.x;
    const int t = threadIdx.x;
    const int wave = t >> 6, lane = t & 63;
    __shared__ float su[DD];
    __shared__ float sm[NCHUNK], sl[NCHUNK];

    if (t < NCHUNK) {
        const float* p = part + ((long)b * NCHUNK + t) * 258;
        sm[t] = p[0];
        sl[t] = p[1];
    }
    __syncthreads();

    float M = -INFINITY;
    #pragma unroll
    for (int i = 0; i < NCHUNK; ++i) M = fmaxf(M, sm[i]);
    float L = 0.f, u = 0.f;
    for (int i = 0; i < NCHUNK; ++i) {
        const float sc = __expf(sm[i] - M);   // exp(-inf - M) = 0: skipped chunks
        L += sl[i] * sc;
        u = fmaf(part[((long)b * NCHUNK + i) * 258 + 2 + t], sc, u);
    }
    su[t] = u / L;
    if (t == 0) { ml[2 * b] = M; ml[2 * b + 1] = L; }
    __syncthreads();

    const f4 s4 = *(const f4*)&su[lane * 4];
    for (int c = wave; c < DD; c += 4) {
        const f4 w4 = *(const f4*)(Wc_w + c * DD + lane * 4);
        float d = dot4(w4, s4);
        d += __shfl_xor(d, 32); d += __shfl_xor(d, 16); d += __shfl_xor(d, 8);
        d += __shfl_xor(d, 4);  d += __shfl_xor(d, 2);  d += __shfl_xor(d, 1);
        if (lane == 0) ctx[b * DD + c] = d + Wc_b[c];
    }
}

// ---------------------------------------------------------------------------
// Kernel 4: alpha[b,s] = exp(energy - M) / L    (f4 elementwise)
// ---------------------------------------------------------------------------
__global__ __launch_bounds__(256) void attn_alpha(
    const float* __restrict__ energy, const float* __restrict__ ml,
    float* __restrict__ alpha)
{
    const int idx = blockIdx.x * 256 + threadIdx.x;  // f4 units
    const int b = idx >> 11;                         // 2048 f4 per batch
    const float M    = ml[2 * b];
    const float invL = 1.0f / ml[2 * b + 1];
    const f4 e4 = __builtin_nontemporal_load(((const f4*)energy) + idx);
    f4 a;
    a.x = __expf(e4.x - M) * invL;
    a.y = __expf(e4.y - M) * invL;
    a.z = __expf(e4.z - M) * invL;
    a.w = __expf(e4.w - M) * invL;
    __builtin_nontemporal_store(a, ((f4*)alpha) + idx);
}

// ---------------------------------------------------------------------------
extern "C" void kernel_launch(void* const* d_in, const int* in_sizes, int n_in,
                              void* d_out, int out_size, void* d_ws, size_t ws_size,
                              hipStream_t stream)
{
    const float* hs    = (const float*)d_in[0];
    const float* ht    = (const float*)d_in[1];
    const int*   slen  = (const int*)d_in[2];
    const float* Wa_w  = (const float*)d_in[3];
    const float* Wa_b  = (const float*)d_in[4];
    const float* Wc_w  = (const float*)d_in[5];
    const float* Wc_b  = (const float*)d_in[6];

    float* alpha = (float*)d_out;                 // [B, S]
    float* ctx   = (float*)d_out + (long)BB * SS; // [B, D_CTX]

    // workspace layout (floats)
    float* ws     = (float*)d_ws;
    float* v      = ws;                        //  8192
    float* c0     = ws + 8192;                 //    32
    float* ml     = ws + 8224;                 //    64
    float* energy = ws + 8288;                 // 262144
    float* part   = ws + 270432;               // 32*64*258 = 528384

    attn_prep<<<dim3(4, BB), 256, 0, stream>>>(ht, Wa_w, Wa_b, v, c0);
    attn_main<<<dim3(NCHUNK, BB), 256, 0, stream>>>(hs, v, c0, slen, energy, part);
    attn_reduce<<<BB, 256, 0, stream>>>(part, Wc_w, Wc_b, ml, ctx);
    attn_alpha<<<(BB * SS / 4) / 256, 256, 0, stream>>>(energy, ml, alpha);
}

// Round 5
// 384.155 us; speedup vs baseline: 1.1320x; 1.0076x over previous
//
#include <hip/hip_runtime.h>
#include <math.h>

// Problem constants (match reference)
constexpr int BB = 32;
constexpr int SS = 8192;
constexpr int DD = 256;          // D_ENC == D_DEC == D_CTX
constexpr int SCHUNK = 128;      // rows per block in main pass (32 rows/wave)
constexpr int NCHUNK = SS / SCHUNK;  // 64 chunks per batch
constexpr float NEG_SLOPE = 0.2f;
constexpr float MASK_VAL = -10000.0f;

// clang ext vector type — required by __builtin_nontemporal_load/store
typedef float f4 __attribute__((ext_vector_type(4)));

__device__ __forceinline__ float dot4(const f4 a, const f4 b) {
    return a.x * b.x + a.y * b.y + a.z * b.z + a.w * b.w;
}

// ---------------------------------------------------------------------------
// Kernel 1: v[b,e] = sum_d ht[b,d] * Wa_w[d,e];  c0[b] = ht[b,:] . Wa_b
// grid (4, BB): each block computes 64 columns, d-loop split 4-ways for MLP.
// ---------------------------------------------------------------------------
__global__ __launch_bounds__(256) void attn_prep(
    const float* __restrict__ ht, const float* __restrict__ Wa_w,
    const float* __restrict__ Wa_b, float* __restrict__ v,
    float* __restrict__ c0)
{
    const int b   = blockIdx.y;
    const int cg  = blockIdx.x;          // column group of 64
    const int t   = threadIdx.x;
    const int col = cg * 64 + (t & 63);
    const int dp  = t >> 6;              // d-partition 0..3
    __shared__ float sht[DD];
    __shared__ float red[4][64];
    sht[t] = ht[b * DD + t];
    __syncthreads();
    float acc = 0.f;
    #pragma unroll 16
    for (int i = 0; i < 64; ++i) {
        const int d = dp * 64 + i;
        acc = fmaf(sht[d], Wa_w[d * DD + col], acc);  // 256B coalesced per dp
    }
    red[dp][t & 63] = acc;
    __syncthreads();
    if (t < 64)
        v[b * DD + col] = red[0][t] + red[1][t] + red[2][t] + red[3][t];

    if (cg == 0) {                       // c0[b] = ht . Wa_b
        __syncthreads();
        float* fr = &red[0][0];
        fr[t] = sht[t] * Wa_b[t];
        __syncthreads();
        for (int s2 = 128; s2 > 0; s2 >>= 1) {
            if (t < s2) fr[t] += fr[t + s2];
            __syncthreads();
        }
        if (t == 0) c0[b] = fr[0];
    }
}

// ---------------------------------------------------------------------------
// Kernel 2: streaming pass over hs. Fully-masked blocks (len>0) exit without
// touching memory at all: their partials/energies are never consumed (alpha
// for masked rows is written as exact 0 by attn_finish, matching the
// reference's exp(-10000-M) fp32 underflow to 0).
// ---------------------------------------------------------------------------
__global__ __launch_bounds__(256) void attn_main(
    const float* __restrict__ hs, const float* __restrict__ v,
    const float* __restrict__ c0, const int* __restrict__ slen,
    float* __restrict__ energy, float* __restrict__ part)
{
    const int b     = blockIdx.y;
    const int chunk = blockIdx.x;
    const int wave  = threadIdx.x >> 6;
    const int lane  = threadIdx.x & 63;
    const int t     = threadIdx.x;

    const int len = slen[b];
    if (len > 0 && chunk * SCHUNK >= len) return;   // fully masked: dead work

    const float c0b = c0[b];
    const f4 vv = *(const f4*)(v + b * DD + lane * 4);

    const int s_base = chunk * SCHUNK + wave * 32;         // 32 rows per wave
    const f4* hrow = (const f4*)(hs + ((long)b * SS + s_base) * DD) + lane;
    constexpr int RSTRIDE = DD / 4;                        // f4 per row

    float m = -INFINITY, l = 0.f;
    f4 u = {0.f, 0.f, 0.f, 0.f};
    float my_e = 0.f;   // lane i (<32) captures energy of row s_base+i

    f4 h0 = __builtin_nontemporal_load(hrow);
    f4 h1 = __builtin_nontemporal_load(hrow + RSTRIDE);

    #pragma unroll 4
    for (int p = 0; p < 16; ++p) {
        f4 n0, n1;
        if (p < 15) {
            n0 = __builtin_nontemporal_load(hrow + (2 * p + 2) * RSTRIDE);
            n1 = __builtin_nontemporal_load(hrow + (2 * p + 3) * RSTRIDE);
        }
        // paired cross-lane reduction of two dot products
        float d0 = dot4(h0, vv);
        float d1 = dot4(h1, vv);
        const float t0 = __shfl_xor(d0, 32);
        const float t1 = __shfl_xor(d1, 32);
        float x = (lane < 32) ? (d0 + t0) : (d1 + t1);
        x += __shfl_xor(x, 16);
        x += __shfl_xor(x, 8);
        x += __shfl_xor(x, 4);
        x += __shfl_xor(x, 2);
        x += __shfl_xor(x, 1);
        const float y = __shfl_xor(x, 32);
        float e0 = ((lane < 32) ? x : y) + c0b;
        float e1 = ((lane < 32) ? y : x) + c0b;

        const int r0 = s_base + 2 * p;
        e0 = e0 > 0.f ? e0 : NEG_SLOPE * e0;
        e1 = e1 > 0.f ? e1 : NEG_SLOPE * e1;
        if (r0 >= len)     e0 = MASK_VAL;
        if (r0 + 1 >= len) e1 = MASK_VAL;
        if (lane == 2 * p)     my_e = e0;
        if (lane == 2 * p + 1) my_e = e1;

        // online softmax update, one rescale per pair
        const float mn = fmaxf(m, fmaxf(e0, e1));
        const float sc = __expf(m - mn);     // first pair: exp(-inf)=0
        const float w0 = __expf(e0 - mn);
        const float w1 = __expf(e1 - mn);
        l = l * sc + w0 + w1;
        u.x = fmaf(w1, h1.x, fmaf(w0, h0.x, u.x * sc));
        u.y = fmaf(w1, h1.y, fmaf(w0, h0.y, u.y * sc));
        u.z = fmaf(w1, h1.z, fmaf(w0, h0.z, u.z * sc));
        u.w = fmaf(w1, h1.w, fmaf(w0, h0.w, u.w * sc));
        m = mn;
        h0 = n0; h1 = n1;
    }
    // coalesced energy store: lanes 0..31 hold rows s_base..s_base+31
    if (lane < 32)
        __builtin_nontemporal_store(my_e, &energy[(long)b * SS + s_base + lane]);

    // combine 4 waves -> one chunk partial
    __shared__ float wm[4], wl[4];
    __shared__ float wu[4][DD];
    if (lane == 0) { wm[wave] = m; wl[wave] = l; }
    *(f4*)&wu[wave][lane * 4] = u;
    __syncthreads();

    const float M  = fmaxf(fmaxf(wm[0], wm[1]), fmaxf(wm[2], wm[3]));
    const float s0 = __expf(wm[0] - M), s1 = __expf(wm[1] - M);
    const float s2 = __expf(wm[2] - M), s3 = __expf(wm[3] - M);
    const float uu = wu[0][t] * s0 + wu[1][t] * s1 + wu[2][t] * s2 + wu[3][t] * s3;

    float* p = part + ((long)b * NCHUNK + chunk) * 258;
    if (t == 0) {
        p[0] = M;
        p[1] = wl[0] * s0 + wl[1] * s1 + wl[2] * s2 + wl[3] * s3;
    }
    p[2 + t] = uu;
}

// ---------------------------------------------------------------------------
// Kernel 3 (fused epilogue), grid (9, BB):
//   x<8 : alpha slice of 1024 rows — (M,L) from partial headers, exact 0 for
//         masked rows (no energy read there)
//   x==8: merge u over valid chunks, context = Wc_w . (u/L) + Wc_b
// Only chunks < nvalid are ever read (masked chunks hold poison).
// ---------------------------------------------------------------------------
__global__ __launch_bounds__(256) void attn_finish(
    const float* __restrict__ part, const float* __restrict__ energy,
    const int* __restrict__ slen, const float* __restrict__ Wc_w,
    const float* __restrict__ Wc_b, float* __restrict__ alpha,
    float* __restrict__ ctx)
{
    const int b = blockIdx.y;
    const int x = blockIdx.x;
    const int t = threadIdx.x;
    const int len = slen[b];
    const int nvalid = (len > 0) ? ((len + SCHUNK - 1) / SCHUNK) : NCHUNK;

    if (x < 8) {
        const int s0 = x * 1024;
        f4* aslice = (f4*)(alpha + (long)b * SS);
        if (len > 0 && s0 >= len) {                 // whole slice masked
            f4 z = {0.f, 0.f, 0.f, 0.f};
            __builtin_nontemporal_store(z, aslice + (s0 >> 2) + t);
            return;
        }
        float M = -INFINITY;
        for (int i = 0; i < nvalid; ++i)
            M = fmaxf(M, part[((long)b * NCHUNK + i) * 258]);
        float L = 0.f;
        for (int i = 0; i < nvalid; ++i) {
            const float* p = part + ((long)b * NCHUNK + i) * 258;
            L += p[1] * __expf(p[0] - M);
        }
        const float invL = 1.0f / L;
        const int s = s0 + t * 4;
        f4 a;
        if (len == 0 || s + 3 < len) {              // fully valid f4
            const f4 e4 = __builtin_nontemporal_load(
                ((const f4*)(energy + (long)b * SS)) + (s >> 2));
            a.x = __expf(e4.x - M) * invL;
            a.y = __expf(e4.y - M) * invL;
            a.z = __expf(e4.z - M) * invL;
            a.w = __expf(e4.w - M) * invL;
        } else if (s >= len) {                      // fully masked f4
            a = (f4){0.f, 0.f, 0.f, 0.f};
        } else {                                    // straddles len
            const f4 e4 = *(((const f4*)(energy + (long)b * SS)) + (s >> 2));
            a.x = (s + 0 < len) ? __expf(e4.x - M) * invL : 0.f;
            a.y = (s + 1 < len) ? __expf(e4.y - M) * invL : 0.f;
            a.z = (s + 2 < len) ? __expf(e4.z - M) * invL : 0.f;
            a.w = (s + 3 < len) ? __expf(e4.w - M) * invL : 0.f;
        }
        __builtin_nontemporal_store(a, aslice + (s >> 2));
        return;
    }

    // x == 8: context
    const int wave = t >> 6, lane = t & 63;
    __shared__ float su[DD];
    float M = -INFINITY;
    for (int i = 0; i < nvalid; ++i)
        M = fmaxf(M, part[((long)b * NCHUNK + i) * 258]);
    float L = 0.f, u = 0.f;
    for (int i = 0; i < nvalid; ++i) {
        const float* p = part + ((long)b * NCHUNK + i) * 258;
        const float sc = __expf(p[0] - M);
        L += p[1] * sc;
        u = fmaf(p[2 + t], sc, u);
    }
    su[t] = u / L;
    __syncthreads();

    const f4 s4 = *(const f4*)&su[lane * 4];
    for (int c = wave; c < DD; c += 4) {
        const f4 w4 = *(const f4*)(Wc_w + c * DD + lane * 4);
        float d = dot4(w4, s4);
        d += __shfl_xor(d, 32); d += __shfl_xor(d, 16); d += __shfl_xor(d, 8);
        d += __shfl_xor(d, 4);  d += __shfl_xor(d, 2);  d += __shfl_xor(d, 1);
        if (lane == 0) ctx[b * DD + c] = d + Wc_b[c];
    }
}

// ---------------------------------------------------------------------------
extern "C" void kernel_launch(void* const* d_in, const int* in_sizes, int n_in,
                              void* d_out, int out_size, void* d_ws, size_t ws_size,
                              hipStream_t stream)
{
    const float* hs    = (const float*)d_in[0];
    const float* ht    = (const float*)d_in[1];
    const int*   slen  = (const int*)d_in[2];
    const float* Wa_w  = (const float*)d_in[3];
    const float* Wa_b  = (const float*)d_in[4];
    const float* Wc_w  = (const float*)d_in[5];
    const float* Wc_b  = (const float*)d_in[6];

    float* alpha = (float*)d_out;                 // [B, S]
    float* ctx   = (float*)d_out + (long)BB * SS; // [B, D_CTX]

    // workspace layout (floats)
    float* ws     = (float*)d_ws;
    float* v      = ws;                        //  8192
    float* c0     = ws + 8192;                 //    32
    float* energy = ws + 8224;                 // 262144
    float* part   = ws + 270368;               // 32*64*258 = 528384

    attn_prep<<<dim3(4, BB), 256, 0, stream>>>(ht, Wa_w, Wa_b, v, c0);
    attn_main<<<dim3(NCHUNK, BB), 256, 0, stream>>>(hs, v, c0, slen, energy, part);
    attn_finish<<<dim3(9, BB), 256, 0, stream>>>(part, energy, slen, Wc_w, Wc_b, alpha, ctx);
}